// Round 4
// baseline (339.666 us; speedup 1.0000x reference)
//
#include <hip/hip_runtime.h>
#include <hip/hip_bf16.h>
#include <hip/hip_cooperative_groups.h>

namespace cg = cooperative_groups;

#define N_NODES 50000
#define N_EDGES 800000
#define D 128
#define BN_EPS 1e-5f
#define ELLW 64            // max in-degree ~40 (Poisson 16); P(>64) negligible
#define PROJ_LDK 136       // padded k-stride (ushorts) to break LDS bank conflicts
#define SPMM_BLOCKS 1564   // legacy fallback grid
#define FUSED_BLOCKS 782   // 782*16 slots = 12512 >= 12500 quad-node slots

#define BINS 128           // node ranges; one single-writer build block each
#define BIN_RANGE 391      // ceil(50000/128); 128*391 = 50048 >= 50000
#define BINCAP 8192        // expected 6250/bin, sigma ~79 -> ~25-sigma slack
#define A_EPT 13           // 256 blk * 256 thr * 13 = 851968 >= 800000
#define A_BLOCKS 256

typedef __attribute__((ext_vector_type(8))) short bf16x8;
typedef __attribute__((ext_vector_type(4))) float f32x4;

__device__ inline float bf_lo(unsigned u) { union { unsigned x; float f; } c; c.x = u << 16; return c.f; }
__device__ inline float bf_hi(unsigned u) { union { unsigned x; float f; } c; c.x = u & 0xffff0000u; return c.f; }
__device__ inline unsigned short f2bf(float f) {
    union { float f; unsigned u; } c; c.f = f;
    unsigned u = c.u;
    u += 0x7fff + ((u >> 16) & 1);   // RNE
    return (unsigned short)(u >> 16);
}
__device__ inline unsigned pack2bf(float a, float b) {
    return (unsigned)f2bf(a) | ((unsigned)f2bf(b) << 16);
}

// ---------- kernel A: radix-partition edges into 128 node-range buckets -----
__global__ __launch_bounds__(256) void bucket_kernel(const int* __restrict__ src,
                                                     const int* __restrict__ dst,
                                                     int* __restrict__ gdbase,
                                                     int* __restrict__ gsbase,
                                                     unsigned* __restrict__ dbkt,
                                                     unsigned short* __restrict__ sbkt) {
    __shared__ int dcnt[BINS], scnt[BINS], dbase[BINS], sbase[BINS];
    const int tid = threadIdx.x;
    if (tid < BINS) { dcnt[tid] = 0; scnt[tid] = 0; }
    __syncthreads();

    const int e0 = blockIdx.x * (256 * A_EPT) + tid;
    int s[A_EPT], t[A_EPT], dr[A_EPT], sr[A_EPT];
    #pragma unroll
    for (int k = 0; k < A_EPT; ++k) {
        int e = e0 + k * 256;
        if (e < N_EDGES) { s[k] = src[e]; t[k] = dst[e]; }
        else             { s[k] = -1;     t[k] = -1;     }
    }
    #pragma unroll
    for (int k = 0; k < A_EPT; ++k) {
        if (t[k] >= 0) dr[k] = atomicAdd(&dcnt[t[k] / BIN_RANGE], 1);
        if (s[k] >= 0) sr[k] = atomicAdd(&scnt[s[k] / BIN_RANGE], 1);
    }
    __syncthreads();
    if (tid < BINS) {
        dbase[tid] = atomicAdd(&gdbase[tid], dcnt[tid]);
        sbase[tid] = atomicAdd(&gsbase[tid], scnt[tid]);
    }
    __syncthreads();
    #pragma unroll
    for (int k = 0; k < A_EPT; ++k) {
        if (t[k] >= 0) {
            int b = t[k] / BIN_RANGE;
            int p = dbase[b] + dr[k];
            if (p < BINCAP)
                dbkt[b * BINCAP + p] = (unsigned)s[k] | ((unsigned)(t[k] - b * BIN_RANGE) << 16);
        }
        if (s[k] >= 0) {
            int b = s[k] / BIN_RANGE;
            int p = sbase[b] + sr[k];
            if (p < BINCAP)
                sbkt[b * BINCAP + p] = (unsigned short)(s[k] - b * BIN_RANGE);
        }
    }
}

// ---------- kernel B: single-writer ELL build + degree histograms -----------
__global__ __launch_bounds__(1024) void build_kernel(const int* __restrict__ gdbase,
                                                     const int* __restrict__ gsbase,
                                                     const unsigned* __restrict__ dbkt,
                                                     const unsigned short* __restrict__ sbkt,
                                                     unsigned short* __restrict__ ell,
                                                     int* __restrict__ cnt,
                                                     int* __restrict__ deg_out) {
    __shared__ int hist[BIN_RANGE];
    const int tid = threadIdx.x;
    const int bin = blockIdx.x & (BINS - 1);
    const int lo  = bin * BIN_RANGE;

    for (int i = tid; i < BIN_RANGE; i += 1024) hist[i] = 0;
    __syncthreads();

    if (blockIdx.x < BINS) {
        int count = gdbase[bin]; if (count > BINCAP) count = BINCAP;
        const unsigned* bkt = dbkt + bin * BINCAP;
        int i = tid;
        for (; i + 3072 < count; i += 4096) {
            unsigned e0 = bkt[i], e1 = bkt[i + 1024], e2 = bkt[i + 2048], e3 = bkt[i + 3072];
            int r0 = atomicAdd(&hist[e0 >> 16], 1);
            int r1 = atomicAdd(&hist[e1 >> 16], 1);
            int r2 = atomicAdd(&hist[e2 >> 16], 1);
            int r3 = atomicAdd(&hist[e3 >> 16], 1);
            if (r0 < ELLW) ell[(size_t)(lo + (e0 >> 16)) * ELLW + r0] = (unsigned short)(e0 & 0xffffu);
            if (r1 < ELLW) ell[(size_t)(lo + (e1 >> 16)) * ELLW + r1] = (unsigned short)(e1 & 0xffffu);
            if (r2 < ELLW) ell[(size_t)(lo + (e2 >> 16)) * ELLW + r2] = (unsigned short)(e2 & 0xffffu);
            if (r3 < ELLW) ell[(size_t)(lo + (e3 >> 16)) * ELLW + r3] = (unsigned short)(e3 & 0xffffu);
        }
        for (; i < count; i += 1024) {
            unsigned e = bkt[i];
            int r = atomicAdd(&hist[e >> 16], 1);
            if (r < ELLW) ell[(size_t)(lo + (e >> 16)) * ELLW + r] = (unsigned short)(e & 0xffffu);
        }
        __syncthreads();
        for (int j = tid; j < BIN_RANGE; j += 1024)
            if (lo + j < N_NODES) cnt[lo + j] = hist[j];
    } else {
        int count = gsbase[bin]; if (count > BINCAP) count = BINCAP;
        const unsigned short* bkt = sbkt + bin * BINCAP;
        int i = tid;
        for (; i + 3072 < count; i += 4096) {
            int v0 = bkt[i], v1 = bkt[i + 1024], v2 = bkt[i + 2048], v3 = bkt[i + 3072];
            atomicAdd(&hist[v0], 1); atomicAdd(&hist[v1], 1);
            atomicAdd(&hist[v2], 1); atomicAdd(&hist[v3], 1);
        }
        for (; i < count; i += 1024) atomicAdd(&hist[bkt[i]], 1);
        __syncthreads();
        for (int j = tid; j < BIN_RANGE; j += 1024)
            if (lo + j < N_NODES) deg_out[lo + j] = hist[j];
    }
}

// ---------- kernel 2: h = bf16((feat * norm_src) @ W) via MFMA --------------
// A-fragments load straight from global: lane (l16,quad) needs feat row
// base+wave*16+l16, cols kk*32+quad*8..+8 — a contiguous 32B slice. No A-tile
// LDS staging, no per-tile barriers (Wt/breg are loop-invariant). 782 blocks
// x 1 tile removes the 391-block 2x CU imbalance.
__global__ __launch_bounds__(256, 2) void proj_kernel(const float* __restrict__ feat,
                                                      const float* __restrict__ W,
                                                      const int* __restrict__ deg_out,
                                                      unsigned short* __restrict__ h) {
    __shared__ unsigned short Wt[D * PROJ_LDK];

    const int tid  = threadIdx.x;
    const int wave = tid >> 6;
    const int lane = tid & 63;
    const int quad = lane >> 4;
    const int l16  = lane & 15;

    for (int idx = tid; idx < D * D; idx += 256) {
        int k = idx >> 7, d = idx & 127;
        Wt[d * PROJ_LDK + k] = f2bf(W[idx]);
    }
    __syncthreads();

    bf16x8 breg[8][4];
    #pragma unroll
    for (int dt = 0; dt < 8; ++dt)
        #pragma unroll
        for (int kk = 0; kk < 4; ++kk)
            breg[dt][kk] = *(const bf16x8*)&Wt[(dt * 16 + l16) * PROJ_LDK + kk * 32 + quad * 8];

    const int n_tiles = (N_NODES + 63) / 64;   // 782
    for (int tile = blockIdx.x; tile < n_tiles; tile += gridDim.x) {
        const int base = tile * 64;
        const int arow = base + wave * 16 + l16;
        const bool rok = arow < N_NODES;
        float nm;
        {
            int dg = rok ? deg_out[arow] : 1;
            nm = rsqrtf((float)(dg < 1 ? 1 : dg));
        }

        f32x4 acc[8];
        #pragma unroll
        for (int dt = 0; dt < 8; ++dt) acc[dt] = (f32x4){0.f, 0.f, 0.f, 0.f};

        #pragma unroll
        for (int kk = 0; kk < 4; ++kk) {
            bf16x8 af;
            if (rok) {
                const float4* fp = (const float4*)(feat + (size_t)arow * D + kk * 32 + quad * 8);
                float4 f0 = fp[0], f1 = fp[1];
                af[0] = (short)f2bf(f0.x * nm); af[1] = (short)f2bf(f0.y * nm);
                af[2] = (short)f2bf(f0.z * nm); af[3] = (short)f2bf(f0.w * nm);
                af[4] = (short)f2bf(f1.x * nm); af[5] = (short)f2bf(f1.y * nm);
                af[6] = (short)f2bf(f1.z * nm); af[7] = (short)f2bf(f1.w * nm);
            } else {
                af = (bf16x8){0, 0, 0, 0, 0, 0, 0, 0};
            }
            #pragma unroll
            for (int dt = 0; dt < 8; ++dt)
                acc[dt] = __builtin_amdgcn_mfma_f32_16x16x32_bf16(af, breg[dt][kk], acc[dt], 0, 0, 0);
        }

        #pragma unroll
        for (int dt = 0; dt < 8; ++dt) {
            #pragma unroll
            for (int r = 0; r < 4; ++r) {
                int n = base + wave * 16 + quad * 4 + r;
                if (n < N_NODES)
                    h[(size_t)n * D + dt * 16 + l16] = f2bf(acc[dt][r]);
            }
        }
    }
}

// ---------- shared gather helper (pair of nodes, 16 lanes per slot) ---------
#define ACCA(v) { accA[0] += bf_lo((v).x); accA[1] += bf_hi((v).x); \
                  accA[2] += bf_lo((v).y); accA[3] += bf_hi((v).y); \
                  accA[4] += bf_lo((v).z); accA[5] += bf_hi((v).z); \
                  accA[6] += bf_lo((v).w); accA[7] += bf_hi((v).w); }
#define ACCB(v) { accB[0] += bf_lo((v).x); accB[1] += bf_hi((v).x); \
                  accB[2] += bf_lo((v).y); accB[3] += bf_hi((v).y); \
                  accB[4] += bf_lo((v).z); accB[5] += bf_hi((v).z); \
                  accB[6] += bf_lo((v).w); accB[7] += bf_hi((v).w); }
#define GA(sid) { uint4 vv = *(const uint4*)(h + (size_t)(sid) * D + coff); ACCA(vv); }
#define GB(sid) { uint4 vv = *(const uint4*)(h + (size_t)(sid) * D + coff); ACCB(vv); }

__device__ __forceinline__ void gather_pair(int n0, int n1,
                                            const int* __restrict__ cnt,
                                            const unsigned short* __restrict__ ell,
                                            const unsigned short* __restrict__ h,
                                            size_t coff, const float* bias, float alpha,
                                            float (&xA)[8], float (&xB)[8],
                                            float (&lsum)[8], float (&lsq)[8]) {
    int dgA = cnt[n0], dgB = cnt[n1];
    int endA = (dgA < ELLW) ? dgA : ELLW;
    int endB = (dgB < ELLW) ? dgB : ELLW;
    const unsigned short* rowA = ell + (size_t)n0 * ELLW;
    const unsigned short* rowB = ell + (size_t)n1 * ELLW;

    float accA[8] = {0,0,0,0,0,0,0,0};
    float accB[8] = {0,0,0,0,0,0,0,0};
    int iA = 0, iB = 0;

    while (iA + 8 <= endA && iB + 8 <= endB) {
        uint4 ra = *(const uint4*)(rowA + iA);
        uint4 rb = *(const uint4*)(rowB + iB);
        GA(ra.x & 0xffff); GA(ra.x >> 16);
        GA(ra.y & 0xffff); GA(ra.y >> 16);
        GA(ra.z & 0xffff); GA(ra.z >> 16);
        GA(ra.w & 0xffff); GA(ra.w >> 16);
        GB(rb.x & 0xffff); GB(rb.x >> 16);
        GB(rb.y & 0xffff); GB(rb.y >> 16);
        GB(rb.z & 0xffff); GB(rb.z >> 16);
        GB(rb.w & 0xffff); GB(rb.w >> 16);
        iA += 8; iB += 8;
    }
    for (; iA + 8 <= endA; iA += 8) {
        uint4 ra = *(const uint4*)(rowA + iA);
        GA(ra.x & 0xffff); GA(ra.x >> 16);
        GA(ra.y & 0xffff); GA(ra.y >> 16);
        GA(ra.z & 0xffff); GA(ra.z >> 16);
        GA(ra.w & 0xffff); GA(ra.w >> 16);
    }
    for (; iB + 8 <= endB; iB += 8) {
        uint4 rb = *(const uint4*)(rowB + iB);
        GB(rb.x & 0xffff); GB(rb.x >> 16);
        GB(rb.y & 0xffff); GB(rb.y >> 16);
        GB(rb.z & 0xffff); GB(rb.z >> 16);
        GB(rb.w & 0xffff); GB(rb.w >> 16);
    }
    for (; iA < endA; ++iA) { GA(rowA[iA]); }
    for (; iB < endB; ++iB) { GB(rowB[iB]); }

    float ndA = rsqrtf((float)(dgA < 1 ? 1 : dgA));
    float ndB = rsqrtf((float)(dgB < 1 ? 1 : dgB));
    #pragma unroll
    for (int j = 0; j < 8; ++j) {
        float va = accA[j] * ndA + bias[j];
        va = (va >= 0.f) ? va : alpha * va;
        xA[j] = va; lsum[j] += va; lsq[j] += va * va;
        float vb = accB[j] * ndB + bias[j];
        vb = (vb >= 0.f) ? vb : alpha * vb;
        xB[j] = vb; lsum[j] += vb; lsq[j] += vb * vb;
    }
}

// ---------- fused kernel 3+4: SpMM + BN stats + grid.sync + BN apply --------
// Each slot (16 lanes) owns 4 consecutive nodes held in registers across a
// cooperative grid sync; final_kernel and the h2 buffer disappear entirely.
// __launch_bounds__(256,4) caps VGPR at 128 -> 4 blocks/CU -> 1024 co-resident
// blocks >= 782, so the cooperative launch is guaranteed to fit.
__global__ __launch_bounds__(256, 4) void spmm_final_kernel(
        const int* __restrict__ cnt,
        const unsigned short* __restrict__ ell,
        const unsigned short* __restrict__ h,
        const float* __restrict__ b,
        const float* __restrict__ a1,
        const float* __restrict__ gamma,
        const float* __restrict__ beta,
        const float* __restrict__ a2,
        float* __restrict__ out,
        float* __restrict__ bn_sum,
        float* __restrict__ bn_sumsq) {
    const int tid  = threadIdx.x;
    const int l16  = tid & 15;
    const int slot = (blockIdx.x * 256 + tid) >> 4;   // quad-node index
    const float alpha = a1[0];
    const size_t coff = (size_t)l16 * 8;

    float bias[8];
    #pragma unroll
    for (int j = 0; j < 8; ++j) bias[j] = b[l16 * 8 + j];

    float lsum[8] = {0,0,0,0,0,0,0,0};
    float lsq[8]  = {0,0,0,0,0,0,0,0};
    float x0[8], x1[8], x2[8], x3[8];

    const bool active = (slot < N_NODES / 4);   // 50000/4 = 12500 exact
    const int nb = slot * 4;
    if (active) {
        gather_pair(nb,     nb + 1, cnt, ell, h, coff, bias, alpha, x0, x1, lsum, lsq);
        gather_pair(nb + 2, nb + 3, cnt, ell, h, coff, bias, alpha, x2, x3, lsum, lsq);
    }

    // BN partials: reduce across 4 slots in wave, then 4 waves, then atomics
    #pragma unroll
    for (int j = 0; j < 8; ++j) {
        lsum[j] += __shfl_xor(lsum[j], 16);
        lsum[j] += __shfl_xor(lsum[j], 32);
        lsq[j]  += __shfl_xor(lsq[j], 16);
        lsq[j]  += __shfl_xor(lsq[j], 32);
    }
    __shared__ float red[4][256];
    const int wave = tid >> 6;
    const int lane = tid & 63;
    if (lane < 16) {
        #pragma unroll
        for (int j = 0; j < 8; ++j) {
            red[wave][l16 * 16 + j]     = lsum[j];
            red[wave][l16 * 16 + 8 + j] = lsq[j];
        }
    }
    __syncthreads();
    {
        float tot = red[0][tid] + red[1][tid] + red[2][tid] + red[3][tid];
        int l = tid >> 4;
        int v = tid & 15;
        int dim = l * 8 + (v & 7);
        int rep = (blockIdx.x & 3) * D;    // 4-way replicated accumulators
        if (v < 8) atomicAdd(&bn_sum[rep + dim], tot);
        else       atomicAdd(&bn_sumsq[rep + dim], tot);
    }
    __threadfence();
    cg::this_grid().sync();

    if (active) {
        const float invN = 1.0f / (float)N_NODES;
        const float alpha2 = a2[0];
        float r0[8], r1[8], r2[8], r3[8];
        #pragma unroll
        for (int j = 0; j < 8; ++j) {
            int d = l16 * 8 + j;
            float sm = bn_sum[d] + bn_sum[D + d] + bn_sum[2 * D + d] + bn_sum[3 * D + d];
            float sq = bn_sumsq[d] + bn_sumsq[D + d] + bn_sumsq[2 * D + d] + bn_sumsq[3 * D + d];
            float mean = sm * invN;
            float var  = sq * invN - mean * mean;
            float inv  = rsqrtf(var + BN_EPS);
            float gs = inv * gamma[d];
            float bt = beta[d] - mean * gs;
            float t;
            t = x0[j] * gs + bt; r0[j] = (t >= 0.f) ? t : alpha2 * t;
            t = x1[j] * gs + bt; r1[j] = (t >= 0.f) ? t : alpha2 * t;
            t = x2[j] * gs + bt; r2[j] = (t >= 0.f) ? t : alpha2 * t;
            t = x3[j] * gs + bt; r3[j] = (t >= 0.f) ? t : alpha2 * t;
        }
        float4* p0 = (float4*)(out + (size_t)nb * D + coff);
        float4* p1 = (float4*)(out + (size_t)(nb + 1) * D + coff);
        float4* p2 = (float4*)(out + (size_t)(nb + 2) * D + coff);
        float4* p3 = (float4*)(out + (size_t)(nb + 3) * D + coff);
        p0[0] = make_float4(r0[0], r0[1], r0[2], r0[3]); p0[1] = make_float4(r0[4], r0[5], r0[6], r0[7]);
        p1[0] = make_float4(r1[0], r1[1], r1[2], r1[3]); p1[1] = make_float4(r1[4], r1[5], r1[6], r1[7]);
        p2[0] = make_float4(r2[0], r2[1], r2[2], r2[3]); p2[1] = make_float4(r2[4], r2[5], r2[6], r2[7]);
        p3[0] = make_float4(r3[0], r3[1], r3[2], r3[3]); p3[1] = make_float4(r3[4], r3[5], r3[6], r3[7]);
    }
}

// ---------- legacy kernels 3 & 4 (fallback if cooperative launch fails) -----
__global__ __launch_bounds__(256) void spmm_kernel(const int* __restrict__ cnt,
                                                   const unsigned short* __restrict__ ell,
                                                   const unsigned short* __restrict__ h,
                                                   const float* __restrict__ b,
                                                   const float* __restrict__ a1,
                                                   unsigned short* __restrict__ h2,
                                                   float* __restrict__ bn_sum,
                                                   float* __restrict__ bn_sumsq) {
    const int tid  = threadIdx.x;
    const int l16  = tid & 15;
    const int slot = (blockIdx.x * 256 + tid) >> 4;
    const float alpha = a1[0];
    const size_t coff = (size_t)l16 * 8;

    float bias[8];
    #pragma unroll
    for (int j = 0; j < 8; ++j) bias[j] = b[l16 * 8 + j];

    float lsum[8] = {0,0,0,0,0,0,0,0};
    float lsq[8]  = {0,0,0,0,0,0,0,0};

    if (slot < N_NODES / 2) {
        const int n0 = slot * 2;
        const int n1 = n0 + 1;
        float xA[8], xB[8];
        gather_pair(n0, n1, cnt, ell, h, coff, bias, alpha, xA, xB, lsum, lsq);
        uint4 oA, oB;
        oA.x = pack2bf(xA[0], xA[1]); oA.y = pack2bf(xA[2], xA[3]);
        oA.z = pack2bf(xA[4], xA[5]); oA.w = pack2bf(xA[6], xA[7]);
        oB.x = pack2bf(xB[0], xB[1]); oB.y = pack2bf(xB[2], xB[3]);
        oB.z = pack2bf(xB[4], xB[5]); oB.w = pack2bf(xB[6], xB[7]);
        *(uint4*)(h2 + (size_t)n0 * D + coff) = oA;
        *(uint4*)(h2 + (size_t)n1 * D + coff) = oB;
    }

    #pragma unroll
    for (int j = 0; j < 8; ++j) {
        lsum[j] += __shfl_xor(lsum[j], 16);
        lsum[j] += __shfl_xor(lsum[j], 32);
        lsq[j]  += __shfl_xor(lsq[j], 16);
        lsq[j]  += __shfl_xor(lsq[j], 32);
    }
    __shared__ float red[4][256];
    const int wave = tid >> 6;
    const int lane = tid & 63;
    if (lane < 16) {
        #pragma unroll
        for (int j = 0; j < 8; ++j) {
            red[wave][l16 * 16 + j]     = lsum[j];
            red[wave][l16 * 16 + 8 + j] = lsq[j];
        }
    }
    __syncthreads();
    {
        float tot = red[0][tid] + red[1][tid] + red[2][tid] + red[3][tid];
        int l = tid >> 4;
        int v = tid & 15;
        int dim = l * 8 + (v & 7);
        int rep = (blockIdx.x & 3) * D;
        if (v < 8) atomicAdd(&bn_sum[rep + dim], tot);
        else       atomicAdd(&bn_sumsq[rep + dim], tot);
    }
}

__global__ __launch_bounds__(256) void final_kernel(const unsigned short* __restrict__ h2,
                                                    const float* __restrict__ bn_sum,
                                                    const float* __restrict__ bn_sumsq,
                                                    const float* __restrict__ gamma,
                                                    const float* __restrict__ beta,
                                                    const float* __restrict__ a2,
                                                    float* __restrict__ out) {
    int i8 = blockIdx.x * 256 + threadIdx.x;
    if (i8 < N_NODES * D / 8) {
        int dbase = (i8 * 8) & (D - 1);
        const float invN = 1.0f / (float)N_NODES;
        const float alpha = a2[0];
        uint4 v = ((const uint4*)h2)[i8];
        float xv[8] = { bf_lo(v.x), bf_hi(v.x), bf_lo(v.y), bf_hi(v.y),
                        bf_lo(v.z), bf_hi(v.z), bf_lo(v.w), bf_hi(v.w) };
        float r[8];
        #pragma unroll
        for (int j = 0; j < 8; ++j) {
            int d = dbase + j;
            float sm = bn_sum[d] + bn_sum[D + d] + bn_sum[2 * D + d] + bn_sum[3 * D + d];
            float sq = bn_sumsq[d] + bn_sumsq[D + d] + bn_sumsq[2 * D + d] + bn_sumsq[3 * D + d];
            float mean = sm * invN;
            float var  = sq * invN - mean * mean;
            float inv  = rsqrtf(var + BN_EPS);
            float t = (xv[j] - mean) * inv * gamma[d] + beta[d];
            r[j] = (t >= 0.f) ? t : alpha * t;
        }
        float4* po = (float4*)(out + (size_t)i8 * 8);
        po[0] = make_float4(r[0], r[1], r[2], r[3]);
        po[1] = make_float4(r[4], r[5], r[6], r[7]);
    }
}

extern "C" void kernel_launch(void* const* d_in, const int* in_sizes, int n_in,
                              void* d_out, int out_size, void* d_ws, size_t ws_size,
                              hipStream_t stream) {
    const float* feat  = (const float*)d_in[0];
    const int*   src   = (const int*)  d_in[1];
    const int*   dst   = (const int*)  d_in[2];
    const float* W     = (const float*)d_in[3];
    const float* b     = (const float*)d_in[4];
    const float* a1    = (const float*)d_in[5];
    const float* gamma = (const float*)d_in[6];
    const float* beta  = (const float*)d_in[7];
    const float* a2    = (const float*)d_in[8];
    float* out = (float*)d_out;

    // Workspace layout (bytes). Only first 5120 B zeroed:
    //   gdbase (512) | gsbase (512) | bn_sum (2048) | bn_sumsq (2048)
    char* ws = (char*)d_ws;
    int*            gdbase    = (int*)(ws + 0);
    int*            gsbase    = (int*)(ws + 512);
    float*          bn_sum    = (float*)(ws + 1024);
    float*          bn_sumsq  = (float*)(ws + 3072);
    int*            cnt       = (int*)(ws + 5120);                // 200000
    int*            deg_out_p = (int*)(ws + 205120);              // 200000
    unsigned short* ell       = (unsigned short*)(ws + 405120);   // 6.4 MB
    unsigned short* h         = (unsigned short*)(ws + 6805120);  // 12.8 MB bf16
    unsigned short* h2        = (unsigned short*)(ws + 19605120); // 12.8 MB (fallback only)
    unsigned*       dbkt      = (unsigned*)(ws + 32405120);       // 128*8192*4 = 4 MB
    unsigned short* sbkt      = (unsigned short*)(ws + 36599424); // 128*8192*2 = 2 MB

    hipMemsetAsync(ws, 0, 5120, stream);

    // A) radix-partition edges into 128 node-range buckets (65k global atomics)
    bucket_kernel<<<A_BLOCKS, 256, 0, stream>>>(src, dst, gdbase, gsbase, dbkt, sbkt);

    // B) single-writer ELL build + degree histograms (zero global atomics)
    build_kernel<<<2 * BINS, 1024, 0, stream>>>(gdbase, gsbase, dbkt, sbkt,
                                                ell, cnt, deg_out_p);

    // 2) projection (MFMA bf16), direct-from-global A fragments, 782 tiles
    proj_kernel<<<FUSED_BLOCKS, 256, 0, stream>>>(feat, W, deg_out_p, h);

    // 3+4) fused SpMM + BN stats + grid sync + BN apply (outputs in registers)
    {
        const int*            cnt_a   = cnt;
        const unsigned short* ell_a   = ell;
        const unsigned short* h_a     = h;
        void* args[] = { (void*)&cnt_a, (void*)&ell_a, (void*)&h_a,
                         (void*)&b, (void*)&a1, (void*)&gamma, (void*)&beta,
                         (void*)&a2, (void*)&out, (void*)&bn_sum, (void*)&bn_sumsq };
        hipError_t err = hipLaunchCooperativeKernel((const void*)spmm_final_kernel,
                                                    dim3(FUSED_BLOCKS), dim3(256),
                                                    args, 0, stream);
        if (err != hipSuccess) {
            // fallback: legacy two-kernel path
            spmm_kernel<<<SPMM_BLOCKS, 256, 0, stream>>>(cnt, ell, h, b, a1, h2,
                                                         bn_sum, bn_sumsq);
            final_kernel<<<(N_NODES * D / 8 + 255) / 256, 256, 0, stream>>>(
                h2, bn_sum, bn_sumsq, gamma, beta, a2, out);
        }
    }
}

// Round 5
// 183.237 us; speedup vs baseline: 1.8537x; 1.8537x over previous
//
#include <hip/hip_runtime.h>
#include <hip/hip_bf16.h>

#define N_NODES 50000
#define N_EDGES 800000
#define D 128
#define BN_EPS 1e-5f
#define ELLW 64            // max in-degree ~40 (Poisson 16); P(>64) negligible
#define PROJ_LDK 136       // padded k-stride (ushorts) to break LDS bank conflicts
#define SPMM_BLOCKS 1564   // 1564*16 slots = 25024 >= 25000 node pairs

#define BINS 128           // node ranges; one single-writer build block each
#define BIN_RANGE 391      // ceil(50000/128); 128*391 = 50048 >= 50000
#define BINCAP 8192        // expected 6250/bin, sigma ~79 -> ~25-sigma slack
#define A_EPT 13           // 256 blk * 256 thr * 13 = 851968 >= 800000
#define A_BLOCKS 256

typedef __attribute__((ext_vector_type(8))) short bf16x8;
typedef __attribute__((ext_vector_type(4))) float f32x4;

__device__ inline float bf_lo(unsigned u) { union { unsigned x; float f; } c; c.x = u << 16; return c.f; }
__device__ inline float bf_hi(unsigned u) { union { unsigned x; float f; } c; c.x = u & 0xffff0000u; return c.f; }
__device__ inline unsigned short f2bf(float f) {
    union { float f; unsigned u; } c; c.f = f;
    unsigned u = c.u;
    u += 0x7fff + ((u >> 16) & 1);   // RNE
    return (unsigned short)(u >> 16);
}
__device__ inline unsigned pack2bf(float a, float b) {
    return (unsigned)f2bf(a) | ((unsigned)f2bf(b) << 16);
}

// ---------- kernel A: radix-partition edges into 128 node-range buckets -----
__global__ __launch_bounds__(256) void bucket_kernel(const int* __restrict__ src,
                                                     const int* __restrict__ dst,
                                                     int* __restrict__ gdbase,
                                                     int* __restrict__ gsbase,
                                                     unsigned* __restrict__ dbkt,
                                                     unsigned short* __restrict__ sbkt) {
    __shared__ int dcnt[BINS], scnt[BINS], dbase[BINS], sbase[BINS];
    const int tid = threadIdx.x;
    if (tid < BINS) { dcnt[tid] = 0; scnt[tid] = 0; }
    __syncthreads();

    const int e0 = blockIdx.x * (256 * A_EPT) + tid;
    int s[A_EPT], t[A_EPT], dr[A_EPT], sr[A_EPT];
    #pragma unroll
    for (int k = 0; k < A_EPT; ++k) {
        int e = e0 + k * 256;
        if (e < N_EDGES) { s[k] = src[e]; t[k] = dst[e]; }
        else             { s[k] = -1;     t[k] = -1;     }
    }
    #pragma unroll
    for (int k = 0; k < A_EPT; ++k) {
        if (t[k] >= 0) dr[k] = atomicAdd(&dcnt[t[k] / BIN_RANGE], 1);
        if (s[k] >= 0) sr[k] = atomicAdd(&scnt[s[k] / BIN_RANGE], 1);
    }
    __syncthreads();
    if (tid < BINS) {
        dbase[tid] = atomicAdd(&gdbase[tid], dcnt[tid]);
        sbase[tid] = atomicAdd(&gsbase[tid], scnt[tid]);
    }
    __syncthreads();
    #pragma unroll
    for (int k = 0; k < A_EPT; ++k) {
        if (t[k] >= 0) {
            int b = t[k] / BIN_RANGE;
            int p = dbase[b] + dr[k];
            if (p < BINCAP)
                dbkt[b * BINCAP + p] = (unsigned)s[k] | ((unsigned)(t[k] - b * BIN_RANGE) << 16);
        }
        if (s[k] >= 0) {
            int b = s[k] / BIN_RANGE;
            int p = sbase[b] + sr[k];
            if (p < BINCAP)
                sbkt[b * BINCAP + p] = (unsigned short)(s[k] - b * BIN_RANGE);
        }
    }
}

// ---------- kernel B: single-writer ELL build + degree histograms -----------
__global__ __launch_bounds__(1024) void build_kernel(const int* __restrict__ gdbase,
                                                     const int* __restrict__ gsbase,
                                                     const unsigned* __restrict__ dbkt,
                                                     const unsigned short* __restrict__ sbkt,
                                                     unsigned short* __restrict__ ell,
                                                     int* __restrict__ cnt,
                                                     int* __restrict__ deg_out) {
    __shared__ int hist[BIN_RANGE];
    const int tid = threadIdx.x;
    const int bin = blockIdx.x & (BINS - 1);
    const int lo  = bin * BIN_RANGE;

    for (int i = tid; i < BIN_RANGE; i += 1024) hist[i] = 0;
    __syncthreads();

    if (blockIdx.x < BINS) {
        int count = gdbase[bin]; if (count > BINCAP) count = BINCAP;
        const unsigned* bkt = dbkt + bin * BINCAP;
        int i = tid;
        for (; i + 3072 < count; i += 4096) {
            unsigned e0 = bkt[i], e1 = bkt[i + 1024], e2 = bkt[i + 2048], e3 = bkt[i + 3072];
            int r0 = atomicAdd(&hist[e0 >> 16], 1);
            int r1 = atomicAdd(&hist[e1 >> 16], 1);
            int r2 = atomicAdd(&hist[e2 >> 16], 1);
            int r3 = atomicAdd(&hist[e3 >> 16], 1);
            if (r0 < ELLW) ell[(size_t)(lo + (e0 >> 16)) * ELLW + r0] = (unsigned short)(e0 & 0xffffu);
            if (r1 < ELLW) ell[(size_t)(lo + (e1 >> 16)) * ELLW + r1] = (unsigned short)(e1 & 0xffffu);
            if (r2 < ELLW) ell[(size_t)(lo + (e2 >> 16)) * ELLW + r2] = (unsigned short)(e2 & 0xffffu);
            if (r3 < ELLW) ell[(size_t)(lo + (e3 >> 16)) * ELLW + r3] = (unsigned short)(e3 & 0xffffu);
        }
        for (; i < count; i += 1024) {
            unsigned e = bkt[i];
            int r = atomicAdd(&hist[e >> 16], 1);
            if (r < ELLW) ell[(size_t)(lo + (e >> 16)) * ELLW + r] = (unsigned short)(e & 0xffffu);
        }
        __syncthreads();
        for (int j = tid; j < BIN_RANGE; j += 1024)
            if (lo + j < N_NODES) cnt[lo + j] = hist[j];
    } else {
        int count = gsbase[bin]; if (count > BINCAP) count = BINCAP;
        const unsigned short* bkt = sbkt + bin * BINCAP;
        int i = tid;
        for (; i + 3072 < count; i += 4096) {
            int v0 = bkt[i], v1 = bkt[i + 1024], v2 = bkt[i + 2048], v3 = bkt[i + 3072];
            atomicAdd(&hist[v0], 1); atomicAdd(&hist[v1], 1);
            atomicAdd(&hist[v2], 1); atomicAdd(&hist[v3], 1);
        }
        for (; i < count; i += 1024) atomicAdd(&hist[bkt[i]], 1);
        __syncthreads();
        for (int j = tid; j < BIN_RANGE; j += 1024)
            if (lo + j < N_NODES) deg_out[lo + j] = hist[j];
    }
}

// ---------- kernel 2: h = bf16((feat * norm_src) @ W) via MFMA --------------
// A-fragments load straight from global: lane (l16,quad) needs feat row
// base+wave*16+l16, cols kk*32+quad*8..+8 — a contiguous 32B slice. No A-tile
// LDS staging, no per-tile barriers (Wt/breg are loop-invariant). 782 blocks
// x 1 tile removes the 391-block 2x CU imbalance.
__global__ __launch_bounds__(256, 2) void proj_kernel(const float* __restrict__ feat,
                                                      const float* __restrict__ W,
                                                      const int* __restrict__ deg_out,
                                                      unsigned short* __restrict__ h) {
    __shared__ unsigned short Wt[D * PROJ_LDK];

    const int tid  = threadIdx.x;
    const int wave = tid >> 6;
    const int lane = tid & 63;
    const int quad = lane >> 4;
    const int l16  = lane & 15;

    for (int idx = tid; idx < D * D; idx += 256) {
        int k = idx >> 7, d = idx & 127;
        Wt[d * PROJ_LDK + k] = f2bf(W[idx]);
    }
    __syncthreads();

    bf16x8 breg[8][4];
    #pragma unroll
    for (int dt = 0; dt < 8; ++dt)
        #pragma unroll
        for (int kk = 0; kk < 4; ++kk)
            breg[dt][kk] = *(const bf16x8*)&Wt[(dt * 16 + l16) * PROJ_LDK + kk * 32 + quad * 8];

    const int n_tiles = (N_NODES + 63) / 64;   // 782
    for (int tile = blockIdx.x; tile < n_tiles; tile += gridDim.x) {
        const int base = tile * 64;
        const int arow = base + wave * 16 + l16;
        const bool rok = arow < N_NODES;
        float nm;
        {
            int dg = rok ? deg_out[arow] : 1;
            nm = rsqrtf((float)(dg < 1 ? 1 : dg));
        }

        f32x4 acc[8];
        #pragma unroll
        for (int dt = 0; dt < 8; ++dt) acc[dt] = (f32x4){0.f, 0.f, 0.f, 0.f};

        #pragma unroll
        for (int kk = 0; kk < 4; ++kk) {
            bf16x8 af;
            if (rok) {
                const float4* fp = (const float4*)(feat + (size_t)arow * D + kk * 32 + quad * 8);
                float4 f0 = fp[0], f1 = fp[1];
                af[0] = (short)f2bf(f0.x * nm); af[1] = (short)f2bf(f0.y * nm);
                af[2] = (short)f2bf(f0.z * nm); af[3] = (short)f2bf(f0.w * nm);
                af[4] = (short)f2bf(f1.x * nm); af[5] = (short)f2bf(f1.y * nm);
                af[6] = (short)f2bf(f1.z * nm); af[7] = (short)f2bf(f1.w * nm);
            } else {
                af = (bf16x8){0, 0, 0, 0, 0, 0, 0, 0};
            }
            #pragma unroll
            for (int dt = 0; dt < 8; ++dt)
                acc[dt] = __builtin_amdgcn_mfma_f32_16x16x32_bf16(af, breg[dt][kk], acc[dt], 0, 0, 0);
        }

        #pragma unroll
        for (int dt = 0; dt < 8; ++dt) {
            #pragma unroll
            for (int r = 0; r < 4; ++r) {
                int n = base + wave * 16 + quad * 4 + r;
                if (n < N_NODES)
                    h[(size_t)n * D + dt * 16 + l16] = f2bf(acc[dt][r]);
            }
        }
    }
}

// ---------- kernel 3: SpMM gather, node-PAIR interleaved per slot ----------
// NOTE (r4 lesson): register-resident fusion with final across a grid sync
// forces a VGPR cap that spills the gather loop to scratch (188 us, FETCH
// 80 MB). Two-kernel form with unconstrained VGPR is 4.7x faster.
#define ACCA(v) { accA[0] += bf_lo((v).x); accA[1] += bf_hi((v).x); \
                  accA[2] += bf_lo((v).y); accA[3] += bf_hi((v).y); \
                  accA[4] += bf_lo((v).z); accA[5] += bf_hi((v).z); \
                  accA[6] += bf_lo((v).w); accA[7] += bf_hi((v).w); }
#define ACCB(v) { accB[0] += bf_lo((v).x); accB[1] += bf_hi((v).x); \
                  accB[2] += bf_lo((v).y); accB[3] += bf_hi((v).y); \
                  accB[4] += bf_lo((v).z); accB[5] += bf_hi((v).z); \
                  accB[6] += bf_lo((v).w); accB[7] += bf_hi((v).w); }
#define GA(sid) { uint4 vv = *(const uint4*)(h + (size_t)(sid) * D + coff); ACCA(vv); }
#define GB(sid) { uint4 vv = *(const uint4*)(h + (size_t)(sid) * D + coff); ACCB(vv); }

__global__ __launch_bounds__(256) void spmm_kernel(const int* __restrict__ cnt,
                                                   const unsigned short* __restrict__ ell,
                                                   const unsigned short* __restrict__ h,
                                                   const float* __restrict__ b,
                                                   const float* __restrict__ a1,
                                                   unsigned short* __restrict__ h2,
                                                   float* __restrict__ bn_sum,
                                                   float* __restrict__ bn_sumsq) {
    const int tid  = threadIdx.x;
    const int l16  = tid & 15;
    const int slot = (blockIdx.x * 256 + tid) >> 4;   // pair index
    const float alpha = a1[0];
    const size_t coff = (size_t)l16 * 8;

    float bias[8];
    #pragma unroll
    for (int j = 0; j < 8; ++j) bias[j] = b[l16 * 8 + j];

    float lsum[8] = {0,0,0,0,0,0,0,0};
    float lsq[8]  = {0,0,0,0,0,0,0,0};

    if (slot < N_NODES / 2) {
        const int n0 = slot * 2;
        const int n1 = n0 + 1;
        int dgA = cnt[n0], dgB = cnt[n1];
        int endA = (dgA < ELLW) ? dgA : ELLW;
        int endB = (dgB < ELLW) ? dgB : ELLW;
        const unsigned short* rowA = ell + (size_t)n0 * ELLW;
        const unsigned short* rowB = ell + (size_t)n1 * ELLW;

        float accA[8] = {0,0,0,0,0,0,0,0};
        float accB[8] = {0,0,0,0,0,0,0,0};
        int iA = 0, iB = 0;

        // joint 8-batches: 2 row loads then 16 independent gathers in flight
        while (iA + 8 <= endA && iB + 8 <= endB) {
            uint4 ra = *(const uint4*)(rowA + iA);
            uint4 rb = *(const uint4*)(rowB + iB);
            GA(ra.x & 0xffff); GA(ra.x >> 16);
            GA(ra.y & 0xffff); GA(ra.y >> 16);
            GA(ra.z & 0xffff); GA(ra.z >> 16);
            GA(ra.w & 0xffff); GA(ra.w >> 16);
            GB(rb.x & 0xffff); GB(rb.x >> 16);
            GB(rb.y & 0xffff); GB(rb.y >> 16);
            GB(rb.z & 0xffff); GB(rb.z >> 16);
            GB(rb.w & 0xffff); GB(rb.w >> 16);
            iA += 8; iB += 8;
        }
        for (; iA + 8 <= endA; iA += 8) {
            uint4 ra = *(const uint4*)(rowA + iA);
            GA(ra.x & 0xffff); GA(ra.x >> 16);
            GA(ra.y & 0xffff); GA(ra.y >> 16);
            GA(ra.z & 0xffff); GA(ra.z >> 16);
            GA(ra.w & 0xffff); GA(ra.w >> 16);
        }
        for (; iB + 8 <= endB; iB += 8) {
            uint4 rb = *(const uint4*)(rowB + iB);
            GB(rb.x & 0xffff); GB(rb.x >> 16);
            GB(rb.y & 0xffff); GB(rb.y >> 16);
            GB(rb.z & 0xffff); GB(rb.z >> 16);
            GB(rb.w & 0xffff); GB(rb.w >> 16);
        }
        for (; iA < endA; ++iA) { GA(rowA[iA]); }
        for (; iB < endB; ++iB) { GB(rowB[iB]); }

        float ndA = rsqrtf((float)(dgA < 1 ? 1 : dgA));
        float ndB = rsqrtf((float)(dgB < 1 ? 1 : dgB));
        float xA[8], xB[8];
        #pragma unroll
        for (int j = 0; j < 8; ++j) {
            float va = accA[j] * ndA + bias[j];
            va = (va >= 0.f) ? va : alpha * va;
            xA[j] = va; lsum[j] += va; lsq[j] += va * va;
            float vb = accB[j] * ndB + bias[j];
            vb = (vb >= 0.f) ? vb : alpha * vb;
            xB[j] = vb; lsum[j] += vb; lsq[j] += vb * vb;
        }
        uint4 oA, oB;
        oA.x = pack2bf(xA[0], xA[1]); oA.y = pack2bf(xA[2], xA[3]);
        oA.z = pack2bf(xA[4], xA[5]); oA.w = pack2bf(xA[6], xA[7]);
        oB.x = pack2bf(xB[0], xB[1]); oB.y = pack2bf(xB[2], xB[3]);
        oB.z = pack2bf(xB[4], xB[5]); oB.w = pack2bf(xB[6], xB[7]);
        *(uint4*)(h2 + (size_t)n0 * D + coff) = oA;
        *(uint4*)(h2 + (size_t)n1 * D + coff) = oB;
    }

    // BN partials: reduce across 4 slots in wave, then 4 waves, then atomics
    #pragma unroll
    for (int j = 0; j < 8; ++j) {
        lsum[j] += __shfl_xor(lsum[j], 16);
        lsum[j] += __shfl_xor(lsum[j], 32);
        lsq[j]  += __shfl_xor(lsq[j], 16);
        lsq[j]  += __shfl_xor(lsq[j], 32);
    }
    __shared__ float red[4][256];
    const int wave = tid >> 6;
    const int lane = tid & 63;
    if (lane < 16) {
        #pragma unroll
        for (int j = 0; j < 8; ++j) {
            red[wave][l16 * 16 + j]     = lsum[j];
            red[wave][l16 * 16 + 8 + j] = lsq[j];
        }
    }
    __syncthreads();
    {
        float tot = red[0][tid] + red[1][tid] + red[2][tid] + red[3][tid];
        int l = tid >> 4;
        int v = tid & 15;
        int dim = l * 8 + (v & 7);
        int rep = (blockIdx.x & 3) * D;    // 4-way replicated accumulators
        if (v < 8) atomicAdd(&bn_sum[rep + dim], tot);
        else       atomicAdd(&bn_sumsq[rep + dim], tot);
    }
}

// ---------- kernel 4: BN finalize + PReLU (bf16 in, fp32 out) ----------
__global__ __launch_bounds__(256) void final_kernel(const unsigned short* __restrict__ h2,
                                                    const float* __restrict__ bn_sum,
                                                    const float* __restrict__ bn_sumsq,
                                                    const float* __restrict__ gamma,
                                                    const float* __restrict__ beta,
                                                    const float* __restrict__ a2,
                                                    float* __restrict__ out) {
    int i8 = blockIdx.x * 256 + threadIdx.x;   // one thread per 8 elements
    if (i8 < N_NODES * D / 8) {
        int dbase = (i8 * 8) & (D - 1);
        const float invN = 1.0f / (float)N_NODES;
        const float alpha = a2[0];
        uint4 v = ((const uint4*)h2)[i8];
        float xv[8] = { bf_lo(v.x), bf_hi(v.x), bf_lo(v.y), bf_hi(v.y),
                        bf_lo(v.z), bf_hi(v.z), bf_lo(v.w), bf_hi(v.w) };
        float r[8];
        #pragma unroll
        for (int j = 0; j < 8; ++j) {
            int d = dbase + j;
            float sm = bn_sum[d] + bn_sum[D + d] + bn_sum[2 * D + d] + bn_sum[3 * D + d];
            float sq = bn_sumsq[d] + bn_sumsq[D + d] + bn_sumsq[2 * D + d] + bn_sumsq[3 * D + d];
            float mean = sm * invN;
            float var  = sq * invN - mean * mean;
            float inv  = rsqrtf(var + BN_EPS);
            float t = (xv[j] - mean) * inv * gamma[d] + beta[d];
            r[j] = (t >= 0.f) ? t : alpha * t;
        }
        float4* po = (float4*)(out + (size_t)i8 * 8);
        po[0] = make_float4(r[0], r[1], r[2], r[3]);
        po[1] = make_float4(r[4], r[5], r[6], r[7]);
    }
}

extern "C" void kernel_launch(void* const* d_in, const int* in_sizes, int n_in,
                              void* d_out, int out_size, void* d_ws, size_t ws_size,
                              hipStream_t stream) {
    const float* feat  = (const float*)d_in[0];
    const int*   src   = (const int*)  d_in[1];
    const int*   dst   = (const int*)  d_in[2];
    const float* W     = (const float*)d_in[3];
    const float* b     = (const float*)d_in[4];
    const float* a1    = (const float*)d_in[5];
    const float* gamma = (const float*)d_in[6];
    const float* beta  = (const float*)d_in[7];
    const float* a2    = (const float*)d_in[8];
    float* out = (float*)d_out;

    // Workspace layout (bytes). Only first 5120 B zeroed:
    //   gdbase (512) | gsbase (512) | bn_sum (2048) | bn_sumsq (2048)
    char* ws = (char*)d_ws;
    int*            gdbase    = (int*)(ws + 0);
    int*            gsbase    = (int*)(ws + 512);
    float*          bn_sum    = (float*)(ws + 1024);
    float*          bn_sumsq  = (float*)(ws + 3072);
    int*            cnt       = (int*)(ws + 5120);                // 200000
    int*            deg_out_p = (int*)(ws + 205120);              // 200000
    unsigned short* ell       = (unsigned short*)(ws + 405120);   // 6.4 MB
    unsigned short* h         = (unsigned short*)(ws + 6805120);  // 12.8 MB bf16
    unsigned short* h2        = (unsigned short*)(ws + 19605120); // 12.8 MB bf16
    unsigned*       dbkt      = (unsigned*)(ws + 32405120);       // 128*8192*4 = 4 MB
    unsigned short* sbkt      = (unsigned short*)(ws + 36599424); // 128*8192*2 = 2 MB

    hipMemsetAsync(ws, 0, 5120, stream);

    // A) radix-partition edges into 128 node-range buckets (65k global atomics)
    bucket_kernel<<<A_BLOCKS, 256, 0, stream>>>(src, dst, gdbase, gsbase, dbkt, sbkt);

    // B) single-writer ELL build + degree histograms (zero global atomics)
    build_kernel<<<2 * BINS, 1024, 0, stream>>>(gdbase, gsbase, dbkt, sbkt,
                                                ell, cnt, deg_out_p);

    // 2) projection (MFMA bf16), direct-from-global A fragments, 782 tiles
    proj_kernel<<<782, 256, 0, stream>>>(feat, W, deg_out_p, h);

    // 3) SpMM gather, node-pair interleaved + BN partials (4-way replicated)
    spmm_kernel<<<SPMM_BLOCKS, 256, 0, stream>>>(cnt, ell, h, b, a1, h2, bn_sum, bn_sumsq);

    // 4) BN finalize + PReLU
    final_kernel<<<(N_NODES * D / 8 + 255) / 256, 256, 0, stream>>>(h2, bn_sum, bn_sumsq,
                                                                    gamma, beta, a2, out);
}

// Round 6
// 179.789 us; speedup vs baseline: 1.8892x; 1.0192x over previous
//
#include <hip/hip_runtime.h>
#include <hip/hip_bf16.h>

#define N_NODES 50000
#define N_EDGES 800000
#define D 128
#define BN_EPS 1e-5f
#define ELLW 64            // max in-degree ~40 (Poisson 16); P(>64) negligible
#define PROJ_LDK 136       // padded k-stride (ushorts) to break LDS bank conflicts
#define SPMM_BLOCKS 1564   // 1564*16 slots = 25024 >= 25000 node pairs
#define PROJ_TILES 782     // ceil(50000/64)

#define BINS 128           // node ranges; one single-writer build block each
#define BIN_RANGE 391      // ceil(50000/128); 128*391 = 50048 >= 50000
#define BINCAP 8192        // expected 6250/bin, sigma ~79 -> ~25-sigma slack
#define A_EPT 13           // 256 blk * 256 thr * 13 = 851968 >= 800000
#define A_BLOCKS 256

typedef __attribute__((ext_vector_type(8))) short bf16x8;
typedef __attribute__((ext_vector_type(4))) float f32x4;

__device__ inline float bf_lo(unsigned u) { union { unsigned x; float f; } c; c.x = u << 16; return c.f; }
__device__ inline float bf_hi(unsigned u) { union { unsigned x; float f; } c; c.x = u & 0xffff0000u; return c.f; }
__device__ inline unsigned short f2bf(float f) {
    union { float f; unsigned u; } c; c.f = f;
    unsigned u = c.u;
    u += 0x7fff + ((u >> 16) & 1);   // RNE
    return (unsigned short)(u >> 16);
}
// HW packed f32->bf16 (RNE), 1 inst for 2 values (no builtin on gfx950)
__device__ inline unsigned cvt_pk_bf16(float lo, float hi) {
    unsigned r;
    asm("v_cvt_pk_bf16_f32 %0, %1, %2" : "=v"(r) : "v"(lo), "v"(hi));
    return r;
}

// ---------- fused kernel A||2: bucket (blocks 0..255) + proj (256..1037) ----
// proj no longer needs deg_out (norm_src folded into SpMM by linearity:
// (feat*norm)@W == norm*(feat@W)), so bucket and proj are independent and
// share one dispatch — saves the serial bucket time + a launch gap.
__global__ __launch_bounds__(256, 2) void bucket_proj_kernel(
        const int* __restrict__ src,
        const int* __restrict__ dst,
        int* __restrict__ gdbase,
        int* __restrict__ gsbase,
        unsigned* __restrict__ dbkt,
        unsigned short* __restrict__ sbkt,
        const float* __restrict__ feat,
        const float* __restrict__ W,
        unsigned short* __restrict__ h) {
    __shared__ int dcnt[BINS], scnt[BINS], dbase[BINS], sbase[BINS];
    __shared__ unsigned short Wt[D * PROJ_LDK];

    const int tid = threadIdx.x;

    if (blockIdx.x < A_BLOCKS) {
        // ---------------- bucket branch: radix-partition edges ----------------
        if (tid < BINS) { dcnt[tid] = 0; scnt[tid] = 0; }
        __syncthreads();

        const int e0 = blockIdx.x * (256 * A_EPT) + tid;
        int s[A_EPT], t[A_EPT], dr[A_EPT], sr[A_EPT];
        #pragma unroll
        for (int k = 0; k < A_EPT; ++k) {
            int e = e0 + k * 256;
            if (e < N_EDGES) { s[k] = src[e]; t[k] = dst[e]; }
            else             { s[k] = -1;     t[k] = -1;     }
        }
        #pragma unroll
        for (int k = 0; k < A_EPT; ++k) {
            if (t[k] >= 0) dr[k] = atomicAdd(&dcnt[t[k] / BIN_RANGE], 1);
            if (s[k] >= 0) sr[k] = atomicAdd(&scnt[s[k] / BIN_RANGE], 1);
        }
        __syncthreads();
        if (tid < BINS) {
            dbase[tid] = atomicAdd(&gdbase[tid], dcnt[tid]);
            sbase[tid] = atomicAdd(&gsbase[tid], scnt[tid]);
        }
        __syncthreads();
        #pragma unroll
        for (int k = 0; k < A_EPT; ++k) {
            if (t[k] >= 0) {
                int bb = t[k] / BIN_RANGE;
                int p = dbase[bb] + dr[k];
                if (p < BINCAP)
                    dbkt[bb * BINCAP + p] = (unsigned)s[k] | ((unsigned)(t[k] - bb * BIN_RANGE) << 16);
            }
            if (s[k] >= 0) {
                int bb = s[k] / BIN_RANGE;
                int p = sbase[bb] + sr[k];
                if (p < BINCAP)
                    sbkt[bb * BINCAP + p] = (unsigned short)(s[k] - bb * BIN_RANGE);
            }
        }
    } else {
        // ---------------- proj branch: h = bf16(feat @ W) via MFMA -----------
        const int tile = blockIdx.x - A_BLOCKS;   // one 64-row tile per block
        const int wave = tid >> 6;
        const int lane = tid & 63;
        const int quad = lane >> 4;
        const int l16  = lane & 15;

        for (int idx = tid; idx < D * D; idx += 256) {
            int k = idx >> 7, d = idx & 127;
            Wt[d * PROJ_LDK + k] = f2bf(W[idx]);
        }
        __syncthreads();

        bf16x8 breg[8][4];
        #pragma unroll
        for (int dt = 0; dt < 8; ++dt)
            #pragma unroll
            for (int kk = 0; kk < 4; ++kk)
                breg[dt][kk] = *(const bf16x8*)&Wt[(dt * 16 + l16) * PROJ_LDK + kk * 32 + quad * 8];

        const int base = tile * 64;
        const int arow = base + wave * 16 + l16;
        const bool rok = arow < N_NODES;

        f32x4 acc[8];
        #pragma unroll
        for (int dt = 0; dt < 8; ++dt) acc[dt] = (f32x4){0.f, 0.f, 0.f, 0.f};

        #pragma unroll
        for (int kk = 0; kk < 4; ++kk) {
            bf16x8 af = (bf16x8){0, 0, 0, 0, 0, 0, 0, 0};
            if (rok) {
                const float4* fp = (const float4*)(feat + (size_t)arow * D + kk * 32 + quad * 8);
                float4 f0 = fp[0], f1 = fp[1];
                unsigned u0 = cvt_pk_bf16(f0.x, f0.y);
                unsigned u1 = cvt_pk_bf16(f0.z, f0.w);
                unsigned u2 = cvt_pk_bf16(f1.x, f1.y);
                unsigned u3 = cvt_pk_bf16(f1.z, f1.w);
                af[0] = (short)(u0 & 0xffff); af[1] = (short)(u0 >> 16);
                af[2] = (short)(u1 & 0xffff); af[3] = (short)(u1 >> 16);
                af[4] = (short)(u2 & 0xffff); af[5] = (short)(u2 >> 16);
                af[6] = (short)(u3 & 0xffff); af[7] = (short)(u3 >> 16);
            }
            #pragma unroll
            for (int dt = 0; dt < 8; ++dt)
                acc[dt] = __builtin_amdgcn_mfma_f32_16x16x32_bf16(af, breg[dt][kk], acc[dt], 0, 0, 0);
        }

        #pragma unroll
        for (int r = 0; r < 4; ++r) {
            int n = base + wave * 16 + quad * 4 + r;
            if (n < N_NODES) {
                unsigned short* hp = h + (size_t)n * D + l16;
                #pragma unroll
                for (int dt = 0; dt < 8; dt += 2) {
                    unsigned pk = cvt_pk_bf16(acc[dt][r], acc[dt + 1][r]);
                    hp[dt * 16]       = (unsigned short)(pk & 0xffff);
                    hp[(dt + 1) * 16] = (unsigned short)(pk >> 16);
                }
            }
        }
    }
}

// ---------- kernel B: single-writer ELL build + nsrc (= rsqrt out-degree) ---
__global__ __launch_bounds__(1024) void build_kernel(const int* __restrict__ gdbase,
                                                     const int* __restrict__ gsbase,
                                                     const unsigned* __restrict__ dbkt,
                                                     const unsigned short* __restrict__ sbkt,
                                                     unsigned short* __restrict__ ell,
                                                     int* __restrict__ cnt,
                                                     float* __restrict__ nsrc) {
    __shared__ int hist[BIN_RANGE];
    const int tid = threadIdx.x;
    const int bin = blockIdx.x & (BINS - 1);
    const int lo  = bin * BIN_RANGE;

    for (int i = tid; i < BIN_RANGE; i += 1024) hist[i] = 0;
    __syncthreads();

    if (blockIdx.x < BINS) {
        int count = gdbase[bin]; if (count > BINCAP) count = BINCAP;
        const unsigned* bkt = dbkt + bin * BINCAP;
        int i = tid;
        for (; i + 3072 < count; i += 4096) {
            unsigned e0 = bkt[i], e1 = bkt[i + 1024], e2 = bkt[i + 2048], e3 = bkt[i + 3072];
            int r0 = atomicAdd(&hist[e0 >> 16], 1);
            int r1 = atomicAdd(&hist[e1 >> 16], 1);
            int r2 = atomicAdd(&hist[e2 >> 16], 1);
            int r3 = atomicAdd(&hist[e3 >> 16], 1);
            if (r0 < ELLW) ell[(size_t)(lo + (e0 >> 16)) * ELLW + r0] = (unsigned short)(e0 & 0xffffu);
            if (r1 < ELLW) ell[(size_t)(lo + (e1 >> 16)) * ELLW + r1] = (unsigned short)(e1 & 0xffffu);
            if (r2 < ELLW) ell[(size_t)(lo + (e2 >> 16)) * ELLW + r2] = (unsigned short)(e2 & 0xffffu);
            if (r3 < ELLW) ell[(size_t)(lo + (e3 >> 16)) * ELLW + r3] = (unsigned short)(e3 & 0xffffu);
        }
        for (; i < count; i += 1024) {
            unsigned e = bkt[i];
            int r = atomicAdd(&hist[e >> 16], 1);
            if (r < ELLW) ell[(size_t)(lo + (e >> 16)) * ELLW + r] = (unsigned short)(e & 0xffffu);
        }
        __syncthreads();
        for (int j = tid; j < BIN_RANGE; j += 1024)
            if (lo + j < N_NODES) cnt[lo + j] = hist[j];
    } else {
        int count = gsbase[bin]; if (count > BINCAP) count = BINCAP;
        const unsigned short* bkt = sbkt + bin * BINCAP;
        int i = tid;
        for (; i + 3072 < count; i += 4096) {
            int v0 = bkt[i], v1 = bkt[i + 1024], v2 = bkt[i + 2048], v3 = bkt[i + 3072];
            atomicAdd(&hist[v0], 1); atomicAdd(&hist[v1], 1);
            atomicAdd(&hist[v2], 1); atomicAdd(&hist[v3], 1);
        }
        for (; i < count; i += 1024) atomicAdd(&hist[bkt[i]], 1);
        __syncthreads();
        for (int j = tid; j < BIN_RANGE; j += 1024)
            if (lo + j < N_NODES) {
                int dg = hist[j];
                nsrc[lo + j] = rsqrtf((float)(dg < 1 ? 1 : dg));
            }
    }
}

// ---------- kernel 3: SpMM gather with folded norm_src ----------------------
// NOTE (r4 lesson): register-resident fusion with final across a grid sync
// forces a VGPR cap that spills the gather loop to scratch. Keep two kernels.
#define ACCA(v, ns) { accA[0] = fmaf(bf_lo((v).x), ns, accA[0]); accA[1] = fmaf(bf_hi((v).x), ns, accA[1]); \
                      accA[2] = fmaf(bf_lo((v).y), ns, accA[2]); accA[3] = fmaf(bf_hi((v).y), ns, accA[3]); \
                      accA[4] = fmaf(bf_lo((v).z), ns, accA[4]); accA[5] = fmaf(bf_hi((v).z), ns, accA[5]); \
                      accA[6] = fmaf(bf_lo((v).w), ns, accA[6]); accA[7] = fmaf(bf_hi((v).w), ns, accA[7]); }
#define ACCB(v, ns) { accB[0] = fmaf(bf_lo((v).x), ns, accB[0]); accB[1] = fmaf(bf_hi((v).x), ns, accB[1]); \
                      accB[2] = fmaf(bf_lo((v).y), ns, accB[2]); accB[3] = fmaf(bf_hi((v).y), ns, accB[3]); \
                      accB[4] = fmaf(bf_lo((v).z), ns, accB[4]); accB[5] = fmaf(bf_hi((v).z), ns, accB[5]); \
                      accB[6] = fmaf(bf_lo((v).w), ns, accB[6]); accB[7] = fmaf(bf_hi((v).w), ns, accB[7]); }
#define GA(sid) { int _s = (int)(sid); uint4 vv = *(const uint4*)(h + (size_t)_s * D + coff); \
                  float ns = nsrc[_s]; ACCA(vv, ns); }
#define GB(sid) { int _s = (int)(sid); uint4 vv = *(const uint4*)(h + (size_t)_s * D + coff); \
                  float ns = nsrc[_s]; ACCB(vv, ns); }

__global__ __launch_bounds__(256) void spmm_kernel(const int* __restrict__ cnt,
                                                   const float* __restrict__ nsrc,
                                                   const unsigned short* __restrict__ ell,
                                                   const unsigned short* __restrict__ h,
                                                   const float* __restrict__ b,
                                                   const float* __restrict__ a1,
                                                   unsigned short* __restrict__ h2,
                                                   float* __restrict__ bn_sum,
                                                   float* __restrict__ bn_sumsq) {
    const int tid  = threadIdx.x;
    const int l16  = tid & 15;
    const int slot = (blockIdx.x * 256 + tid) >> 4;   // pair index
    const float alpha = a1[0];
    const size_t coff = (size_t)l16 * 8;

    float bias[8];
    #pragma unroll
    for (int j = 0; j < 8; ++j) bias[j] = b[l16 * 8 + j];

    float lsum[8] = {0,0,0,0,0,0,0,0};
    float lsq[8]  = {0,0,0,0,0,0,0,0};

    if (slot < N_NODES / 2) {
        const int n0 = slot * 2;
        const int n1 = n0 + 1;
        int dgA = cnt[n0], dgB = cnt[n1];
        int endA = (dgA < ELLW) ? dgA : ELLW;
        int endB = (dgB < ELLW) ? dgB : ELLW;
        const unsigned short* rowA = ell + (size_t)n0 * ELLW;
        const unsigned short* rowB = ell + (size_t)n1 * ELLW;

        float accA[8] = {0,0,0,0,0,0,0,0};
        float accB[8] = {0,0,0,0,0,0,0,0};
        int iA = 0, iB = 0;

        // joint 8-batches: 2 row loads then 16 independent gathers in flight
        while (iA + 8 <= endA && iB + 8 <= endB) {
            uint4 ra = *(const uint4*)(rowA + iA);
            uint4 rb = *(const uint4*)(rowB + iB);
            GA(ra.x & 0xffff); GA(ra.x >> 16);
            GA(ra.y & 0xffff); GA(ra.y >> 16);
            GA(ra.z & 0xffff); GA(ra.z >> 16);
            GA(ra.w & 0xffff); GA(ra.w >> 16);
            GB(rb.x & 0xffff); GB(rb.x >> 16);
            GB(rb.y & 0xffff); GB(rb.y >> 16);
            GB(rb.z & 0xffff); GB(rb.z >> 16);
            GB(rb.w & 0xffff); GB(rb.w >> 16);
            iA += 8; iB += 8;
        }
        for (; iA + 8 <= endA; iA += 8) {
            uint4 ra = *(const uint4*)(rowA + iA);
            GA(ra.x & 0xffff); GA(ra.x >> 16);
            GA(ra.y & 0xffff); GA(ra.y >> 16);
            GA(ra.z & 0xffff); GA(ra.z >> 16);
            GA(ra.w & 0xffff); GA(ra.w >> 16);
        }
        for (; iB + 8 <= endB; iB += 8) {
            uint4 rb = *(const uint4*)(rowB + iB);
            GB(rb.x & 0xffff); GB(rb.x >> 16);
            GB(rb.y & 0xffff); GB(rb.y >> 16);
            GB(rb.z & 0xffff); GB(rb.z >> 16);
            GB(rb.w & 0xffff); GB(rb.w >> 16);
        }
        for (; iA < endA; ++iA) { GA(rowA[iA]); }
        for (; iB < endB; ++iB) { GB(rowB[iB]); }

        float ndA = rsqrtf((float)(dgA < 1 ? 1 : dgA));
        float ndB = rsqrtf((float)(dgB < 1 ? 1 : dgB));
        float xA[8], xB[8];
        #pragma unroll
        for (int j = 0; j < 8; ++j) {
            float va = accA[j] * ndA + bias[j];
            va = (va >= 0.f) ? va : alpha * va;
            xA[j] = va; lsum[j] += va; lsq[j] += va * va;
            float vb = accB[j] * ndB + bias[j];
            vb = (vb >= 0.f) ? vb : alpha * vb;
            xB[j] = vb; lsum[j] += vb; lsq[j] += vb * vb;
        }
        uint4 oA, oB;
        oA.x = cvt_pk_bf16(xA[0], xA[1]); oA.y = cvt_pk_bf16(xA[2], xA[3]);
        oA.z = cvt_pk_bf16(xA[4], xA[5]); oA.w = cvt_pk_bf16(xA[6], xA[7]);
        oB.x = cvt_pk_bf16(xB[0], xB[1]); oB.y = cvt_pk_bf16(xB[2], xB[3]);
        oB.z = cvt_pk_bf16(xB[4], xB[5]); oB.w = cvt_pk_bf16(xB[6], xB[7]);
        *(uint4*)(h2 + (size_t)n0 * D + coff) = oA;
        *(uint4*)(h2 + (size_t)n1 * D + coff) = oB;
    }

    // BN partials: reduce across 4 slots in wave, then 4 waves, then atomics
    #pragma unroll
    for (int j = 0; j < 8; ++j) {
        lsum[j] += __shfl_xor(lsum[j], 16);
        lsum[j] += __shfl_xor(lsum[j], 32);
        lsq[j]  += __shfl_xor(lsq[j], 16);
        lsq[j]  += __shfl_xor(lsq[j], 32);
    }
    __shared__ float red[4][256];
    const int wave = tid >> 6;
    const int lane = tid & 63;
    if (lane < 16) {
        #pragma unroll
        for (int j = 0; j < 8; ++j) {
            red[wave][l16 * 16 + j]     = lsum[j];
            red[wave][l16 * 16 + 8 + j] = lsq[j];
        }
    }
    __syncthreads();
    {
        float tot = red[0][tid] + red[1][tid] + red[2][tid] + red[3][tid];
        int l = tid >> 4;
        int v = tid & 15;
        int dim = l * 8 + (v & 7);
        int rep = (blockIdx.x & 3) * D;    // 4-way replicated accumulators
        if (v < 8) atomicAdd(&bn_sum[rep + dim], tot);
        else       atomicAdd(&bn_sumsq[rep + dim], tot);
    }
}

// ---------- kernel 4: BN finalize + PReLU (bf16 in, fp32 out) ----------
__global__ __launch_bounds__(256) void final_kernel(const unsigned short* __restrict__ h2,
                                                    const float* __restrict__ bn_sum,
                                                    const float* __restrict__ bn_sumsq,
                                                    const float* __restrict__ gamma,
                                                    const float* __restrict__ beta,
                                                    const float* __restrict__ a2,
                                                    float* __restrict__ out) {
    int i8 = blockIdx.x * 256 + threadIdx.x;   // one thread per 8 elements
    if (i8 < N_NODES * D / 8) {
        int dbase = (i8 * 8) & (D - 1);
        const float invN = 1.0f / (float)N_NODES;
        const float alpha = a2[0];
        uint4 v = ((const uint4*)h2)[i8];
        float xv[8] = { bf_lo(v.x), bf_hi(v.x), bf_lo(v.y), bf_hi(v.y),
                        bf_lo(v.z), bf_hi(v.z), bf_lo(v.w), bf_hi(v.w) };
        float r[8];
        #pragma unroll
        for (int j = 0; j < 8; ++j) {
            int d = dbase + j;
            float sm = bn_sum[d] + bn_sum[D + d] + bn_sum[2 * D + d] + bn_sum[3 * D + d];
            float sq = bn_sumsq[d] + bn_sumsq[D + d] + bn_sumsq[2 * D + d] + bn_sumsq[3 * D + d];
            float mean = sm * invN;
            float var  = sq * invN - mean * mean;
            float inv  = rsqrtf(var + BN_EPS);
            float t = (xv[j] - mean) * inv * gamma[d] + beta[d];
            r[j] = (t >= 0.f) ? t : alpha * t;
        }
        float4* po = (float4*)(out + (size_t)i8 * 8);
        po[0] = make_float4(r[0], r[1], r[2], r[3]);
        po[1] = make_float4(r[4], r[5], r[6], r[7]);
    }
}

extern "C" void kernel_launch(void* const* d_in, const int* in_sizes, int n_in,
                              void* d_out, int out_size, void* d_ws, size_t ws_size,
                              hipStream_t stream) {
    const float* feat  = (const float*)d_in[0];
    const int*   src   = (const int*)  d_in[1];
    const int*   dst   = (const int*)  d_in[2];
    const float* W     = (const float*)d_in[3];
    const float* b     = (const float*)d_in[4];
    const float* a1    = (const float*)d_in[5];
    const float* gamma = (const float*)d_in[6];
    const float* beta  = (const float*)d_in[7];
    const float* a2    = (const float*)d_in[8];
    float* out = (float*)d_out;

    // Workspace layout (bytes). Only first 5120 B zeroed:
    //   gdbase (512) | gsbase (512) | bn_sum (2048) | bn_sumsq (2048)
    char* ws = (char*)d_ws;
    int*            gdbase    = (int*)(ws + 0);
    int*            gsbase    = (int*)(ws + 512);
    float*          bn_sum    = (float*)(ws + 1024);
    float*          bn_sumsq  = (float*)(ws + 3072);
    int*            cnt       = (int*)(ws + 5120);                // 200192
    float*          nsrc      = (float*)(ws + 205120);            // 200192
    unsigned short* ell       = (unsigned short*)(ws + 405120);   // 6.4 MB
    unsigned short* h         = (unsigned short*)(ws + 6805120);  // 12.8 MB bf16
    unsigned short* h2        = (unsigned short*)(ws + 19605120); // 12.8 MB bf16
    unsigned*       dbkt      = (unsigned*)(ws + 32405120);       // 128*8192*4 = 4 MB
    unsigned short* sbkt      = (unsigned short*)(ws + 36599424); // 128*8192*2 = 2 MB

    hipMemsetAsync(ws, 0, 5120, stream);

    // A||2) bucket (256 blocks) concurrent with proj (782 blocks)
    bucket_proj_kernel<<<A_BLOCKS + PROJ_TILES, 256, 0, stream>>>(
        src, dst, gdbase, gsbase, dbkt, sbkt, feat, W, h);

    // B) single-writer ELL build + cnt + nsrc (zero global atomics)
    build_kernel<<<2 * BINS, 1024, 0, stream>>>(gdbase, gsbase, dbkt, sbkt,
                                                ell, cnt, nsrc);

    // 3) SpMM gather with folded norm_src + BN partials (4-way replicated)
    spmm_kernel<<<SPMM_BLOCKS, 256, 0, stream>>>(cnt, nsrc, ell, h, b, a1, h2,
                                                 bn_sum, bn_sumsq);

    // 4) BN finalize + PReLU
    final_kernel<<<(N_NODES * D / 8 + 255) / 256, 256, 0, stream>>>(h2, bn_sum, bn_sumsq,
                                                                    gamma, beta, a2, out);
}

// Round 7
// 176.825 us; speedup vs baseline: 1.9209x; 1.0168x over previous
//
#include <hip/hip_runtime.h>
#include <hip/hip_bf16.h>

#define N_NODES 50000
#define N_EDGES 800000
#define D 128
#define BN_EPS 1e-5f
#define ELLW 64            // max in-degree ~40 (Poisson 16); P(>64) negligible
#define PROJ_LDK 136       // padded k-stride (ushorts) to break LDS bank conflicts
#define SPMM_BLOCKS 1564   // 1564*16 slots = 25024 >= 25000 node pairs
#define PROJ_TILES 782     // ceil(50000/64)

#define BINS 128           // node ranges; one single-writer build block each
#define BIN_RANGE 391      // ceil(50000/128); 128*391 = 50048 >= 50000
#define BINCAP 8192        // expected 6250/bin, sigma ~79 -> ~25-sigma slack
#define A_EPT 13           // 256 blk * 256 thr * 13 = 851968 >= 800000
#define A_BLOCKS 256

typedef __attribute__((ext_vector_type(8))) short bf16x8;
typedef __attribute__((ext_vector_type(4))) float f32x4;

__device__ inline float bf_lo(unsigned u) { union { unsigned x; float f; } c; c.x = u << 16; return c.f; }
__device__ inline float bf_hi(unsigned u) { union { unsigned x; float f; } c; c.x = u & 0xffff0000u; return c.f; }
__device__ inline unsigned short f2bf(float f) {
    union { float f; unsigned u; } c; c.f = f;
    unsigned u = c.u;
    u += 0x7fff + ((u >> 16) & 1);   // RNE
    return (unsigned short)(u >> 16);
}
// HW packed f32->bf16 (RNE), 1 inst for 2 values (no builtin on gfx950)
__device__ inline unsigned cvt_pk_bf16(float lo, float hi) {
    unsigned r;
    asm("v_cvt_pk_bf16_f32 %0, %1, %2" : "=v"(r) : "v"(lo), "v"(hi));
    return r;
}

// ---------- fused kernel A||2: bucket (blocks 0..255) + proj (256..1037) ----
// proj is independent of the edge pipeline (norm_src applied later by build's
// in-place h-scale), so bucket and proj share one dispatch.
__global__ __launch_bounds__(256, 2) void bucket_proj_kernel(
        const int* __restrict__ src,
        const int* __restrict__ dst,
        int* __restrict__ gdbase,
        int* __restrict__ gsbase,
        unsigned* __restrict__ dbkt,
        unsigned short* __restrict__ sbkt,
        const float* __restrict__ feat,
        const float* __restrict__ W,
        unsigned short* __restrict__ h) {
    __shared__ int dcnt[BINS], scnt[BINS], dbase[BINS], sbase[BINS];
    __shared__ unsigned short Wt[D * PROJ_LDK];

    const int tid = threadIdx.x;

    if (blockIdx.x < A_BLOCKS) {
        // ---------------- bucket branch: radix-partition edges ----------------
        if (tid < BINS) { dcnt[tid] = 0; scnt[tid] = 0; }
        __syncthreads();

        const int e0 = blockIdx.x * (256 * A_EPT) + tid;
        int s[A_EPT], t[A_EPT], dr[A_EPT], sr[A_EPT];
        #pragma unroll
        for (int k = 0; k < A_EPT; ++k) {
            int e = e0 + k * 256;
            if (e < N_EDGES) { s[k] = src[e]; t[k] = dst[e]; }
            else             { s[k] = -1;     t[k] = -1;     }
        }
        #pragma unroll
        for (int k = 0; k < A_EPT; ++k) {
            if (t[k] >= 0) dr[k] = atomicAdd(&dcnt[t[k] / BIN_RANGE], 1);
            if (s[k] >= 0) sr[k] = atomicAdd(&scnt[s[k] / BIN_RANGE], 1);
        }
        __syncthreads();
        if (tid < BINS) {
            dbase[tid] = atomicAdd(&gdbase[tid], dcnt[tid]);
            sbase[tid] = atomicAdd(&gsbase[tid], scnt[tid]);
        }
        __syncthreads();
        #pragma unroll
        for (int k = 0; k < A_EPT; ++k) {
            if (t[k] >= 0) {
                int bb = t[k] / BIN_RANGE;
                int p = dbase[bb] + dr[k];
                if (p < BINCAP)
                    dbkt[bb * BINCAP + p] = (unsigned)s[k] | ((unsigned)(t[k] - bb * BIN_RANGE) << 16);
            }
            if (s[k] >= 0) {
                int bb = s[k] / BIN_RANGE;
                int p = sbase[bb] + sr[k];
                if (p < BINCAP)
                    sbkt[bb * BINCAP + p] = (unsigned short)(s[k] - bb * BIN_RANGE);
            }
        }
    } else {
        // ---------------- proj branch: h = bf16(feat @ W) via MFMA -----------
        const int tile = blockIdx.x - A_BLOCKS;   // one 64-row tile per block
        const int wave = tid >> 6;
        const int lane = tid & 63;
        const int quad = lane >> 4;
        const int l16  = lane & 15;

        for (int idx = tid; idx < D * D; idx += 256) {
            int k = idx >> 7, d = idx & 127;
            Wt[d * PROJ_LDK + k] = f2bf(W[idx]);
        }
        __syncthreads();

        bf16x8 breg[8][4];
        #pragma unroll
        for (int dt = 0; dt < 8; ++dt)
            #pragma unroll
            for (int kk = 0; kk < 4; ++kk)
                breg[dt][kk] = *(const bf16x8*)&Wt[(dt * 16 + l16) * PROJ_LDK + kk * 32 + quad * 8];

        const int base = tile * 64;
        const int arow = base + wave * 16 + l16;
        const bool rok = arow < N_NODES;

        f32x4 acc[8];
        #pragma unroll
        for (int dt = 0; dt < 8; ++dt) acc[dt] = (f32x4){0.f, 0.f, 0.f, 0.f};

        #pragma unroll
        for (int kk = 0; kk < 4; ++kk) {
            bf16x8 af = (bf16x8){0, 0, 0, 0, 0, 0, 0, 0};
            if (rok) {
                const float4* fp = (const float4*)(feat + (size_t)arow * D + kk * 32 + quad * 8);
                float4 f0 = fp[0], f1 = fp[1];
                unsigned u0 = cvt_pk_bf16(f0.x, f0.y);
                unsigned u1 = cvt_pk_bf16(f0.z, f0.w);
                unsigned u2 = cvt_pk_bf16(f1.x, f1.y);
                unsigned u3 = cvt_pk_bf16(f1.z, f1.w);
                af[0] = (short)(u0 & 0xffff); af[1] = (short)(u0 >> 16);
                af[2] = (short)(u1 & 0xffff); af[3] = (short)(u1 >> 16);
                af[4] = (short)(u2 & 0xffff); af[5] = (short)(u2 >> 16);
                af[6] = (short)(u3 & 0xffff); af[7] = (short)(u3 >> 16);
            }
            #pragma unroll
            for (int dt = 0; dt < 8; ++dt)
                acc[dt] = __builtin_amdgcn_mfma_f32_16x16x32_bf16(af, breg[dt][kk], acc[dt], 0, 0, 0);
        }

        #pragma unroll
        for (int r = 0; r < 4; ++r) {
            int n = base + wave * 16 + quad * 4 + r;
            if (n < N_NODES) {
                unsigned short* hp = h + (size_t)n * D + l16;
                #pragma unroll
                for (int dt = 0; dt < 8; dt += 2) {
                    unsigned pk = cvt_pk_bf16(acc[dt][r], acc[dt + 1][r]);
                    hp[dt * 16]       = (unsigned short)(pk & 0xffff);
                    hp[(dt + 1) * 16] = (unsigned short)(pk >> 16);
                }
            }
        }
    }
}

// ---------- kernel B: single-writer ELL build + in-place h *= norm_src ------
// Blocks 0..127: ELL + cnt from dst buckets. Blocks 128..255: out-degree hist
// from src buckets, then scale this range's h rows by rsqrt(deg) in place
// (12.8 MB r/w spread over 128 blocks) — removes the per-edge nsrc load that
// regressed spmm in r6.
__global__ __launch_bounds__(1024) void build_kernel(const int* __restrict__ gdbase,
                                                     const int* __restrict__ gsbase,
                                                     const unsigned* __restrict__ dbkt,
                                                     const unsigned short* __restrict__ sbkt,
                                                     unsigned short* __restrict__ ell,
                                                     int* __restrict__ cnt,
                                                     unsigned short* __restrict__ h) {
    __shared__ int hist[BIN_RANGE];
    const int tid = threadIdx.x;
    const int bin = blockIdx.x & (BINS - 1);
    const int lo  = bin * BIN_RANGE;

    for (int i = tid; i < BIN_RANGE; i += 1024) hist[i] = 0;
    __syncthreads();

    if (blockIdx.x < BINS) {
        int count = gdbase[bin]; if (count > BINCAP) count = BINCAP;
        const unsigned* bkt = dbkt + bin * BINCAP;
        int i = tid;
        for (; i + 3072 < count; i += 4096) {
            unsigned e0 = bkt[i], e1 = bkt[i + 1024], e2 = bkt[i + 2048], e3 = bkt[i + 3072];
            int r0 = atomicAdd(&hist[e0 >> 16], 1);
            int r1 = atomicAdd(&hist[e1 >> 16], 1);
            int r2 = atomicAdd(&hist[e2 >> 16], 1);
            int r3 = atomicAdd(&hist[e3 >> 16], 1);
            if (r0 < ELLW) ell[(size_t)(lo + (e0 >> 16)) * ELLW + r0] = (unsigned short)(e0 & 0xffffu);
            if (r1 < ELLW) ell[(size_t)(lo + (e1 >> 16)) * ELLW + r1] = (unsigned short)(e1 & 0xffffu);
            if (r2 < ELLW) ell[(size_t)(lo + (e2 >> 16)) * ELLW + r2] = (unsigned short)(e2 & 0xffffu);
            if (r3 < ELLW) ell[(size_t)(lo + (e3 >> 16)) * ELLW + r3] = (unsigned short)(e3 & 0xffffu);
        }
        for (; i < count; i += 1024) {
            unsigned e = bkt[i];
            int r = atomicAdd(&hist[e >> 16], 1);
            if (r < ELLW) ell[(size_t)(lo + (e >> 16)) * ELLW + r] = (unsigned short)(e & 0xffffu);
        }
        __syncthreads();
        for (int j = tid; j < BIN_RANGE; j += 1024)
            if (lo + j < N_NODES) cnt[lo + j] = hist[j];
    } else {
        int count = gsbase[bin]; if (count > BINCAP) count = BINCAP;
        const unsigned short* bkt = sbkt + bin * BINCAP;
        int i = tid;
        for (; i + 3072 < count; i += 4096) {
            int v0 = bkt[i], v1 = bkt[i + 1024], v2 = bkt[i + 2048], v3 = bkt[i + 3072];
            atomicAdd(&hist[v0], 1); atomicAdd(&hist[v1], 1);
            atomicAdd(&hist[v2], 1); atomicAdd(&hist[v3], 1);
        }
        for (; i < count; i += 1024) atomicAdd(&hist[bkt[i]], 1);
        __syncthreads();
        // scale h rows of this src range by rsqrt(max(deg,1)), in place
        for (int idx = tid; idx < BIN_RANGE * 16; idx += 1024) {
            int j = idx >> 4, c = idx & 15;
            int n = lo + j;
            if (n < N_NODES) {
                int dg = hist[j];
                float ns = rsqrtf((float)(dg < 1 ? 1 : dg));
                uint4* hp = (uint4*)(h + (size_t)n * D) + c;
                uint4 v = *hp;
                uint4 o;
                o.x = cvt_pk_bf16(bf_lo(v.x) * ns, bf_hi(v.x) * ns);
                o.y = cvt_pk_bf16(bf_lo(v.y) * ns, bf_hi(v.y) * ns);
                o.z = cvt_pk_bf16(bf_lo(v.z) * ns, bf_hi(v.z) * ns);
                o.w = cvt_pk_bf16(bf_lo(v.w) * ns, bf_hi(v.w) * ns);
                *hp = o;
            }
        }
    }
}

// ---------- kernel 3: SpMM gather, forced 16-deep MLP per joint batch -------
// NOTE (r4 lesson): register-resident fusion with final across a grid sync
// forces a VGPR cap that spills the gather loop to scratch. Keep two kernels.
// r6 lesson: accumulate-immediately source let the compiler throttle to ~7
// loads in flight (VGPR 76). Named g0..g7/k0..k7 force all 16 loads issued
// before any accumulation.
#define ACC8(a, v) { a[0] += bf_lo((v).x); a[1] += bf_hi((v).x); \
                     a[2] += bf_lo((v).y); a[3] += bf_hi((v).y); \
                     a[4] += bf_lo((v).z); a[5] += bf_hi((v).z); \
                     a[6] += bf_lo((v).w); a[7] += bf_hi((v).w); }
#define LDH(sid) (*(const uint4*)(h + (size_t)((sid)) * D + coff))

__global__ __launch_bounds__(256) void spmm_kernel(const int* __restrict__ cnt,
                                                   const unsigned short* __restrict__ ell,
                                                   const unsigned short* __restrict__ h,
                                                   const float* __restrict__ b,
                                                   const float* __restrict__ a1,
                                                   unsigned short* __restrict__ h2,
                                                   float* __restrict__ bn_sum,
                                                   float* __restrict__ bn_sumsq) {
    const int tid  = threadIdx.x;
    const int l16  = tid & 15;
    const int slot = (blockIdx.x * 256 + tid) >> 4;   // pair index
    const size_t coff = (size_t)l16 * 8;

    float lsum[8] = {0,0,0,0,0,0,0,0};
    float lsq[8]  = {0,0,0,0,0,0,0,0};

    if (slot < N_NODES / 2) {
        const int n0 = slot * 2;
        const int n1 = n0 + 1;
        int dgA = cnt[n0], dgB = cnt[n1];
        int endA = (dgA < ELLW) ? dgA : ELLW;
        int endB = (dgB < ELLW) ? dgB : ELLW;
        const unsigned short* rowA = ell + (size_t)n0 * ELLW;
        const unsigned short* rowB = ell + (size_t)n1 * ELLW;

        float accA[8] = {0,0,0,0,0,0,0,0};
        float accB[8] = {0,0,0,0,0,0,0,0};
        int iA = 0, iB = 0;

        // joint 8-batches: 2 row loads then 16 named gathers in flight
        while (iA + 8 <= endA && iB + 8 <= endB) {
            uint4 ra = *(const uint4*)(rowA + iA);
            uint4 rb = *(const uint4*)(rowB + iB);
            uint4 g0 = LDH(ra.x & 0xffff), g1 = LDH(ra.x >> 16);
            uint4 g2 = LDH(ra.y & 0xffff), g3 = LDH(ra.y >> 16);
            uint4 g4 = LDH(ra.z & 0xffff), g5 = LDH(ra.z >> 16);
            uint4 g6 = LDH(ra.w & 0xffff), g7 = LDH(ra.w >> 16);
            uint4 k0 = LDH(rb.x & 0xffff), k1 = LDH(rb.x >> 16);
            uint4 k2 = LDH(rb.y & 0xffff), k3 = LDH(rb.y >> 16);
            uint4 k4 = LDH(rb.z & 0xffff), k5 = LDH(rb.z >> 16);
            uint4 k6 = LDH(rb.w & 0xffff), k7 = LDH(rb.w >> 16);
            ACC8(accA, g0); ACC8(accA, g1); ACC8(accA, g2); ACC8(accA, g3);
            ACC8(accA, g4); ACC8(accA, g5); ACC8(accA, g6); ACC8(accA, g7);
            ACC8(accB, k0); ACC8(accB, k1); ACC8(accB, k2); ACC8(accB, k3);
            ACC8(accB, k4); ACC8(accB, k5); ACC8(accB, k6); ACC8(accB, k7);
            iA += 8; iB += 8;
        }
        for (; iA + 8 <= endA; iA += 8) {
            uint4 ra = *(const uint4*)(rowA + iA);
            uint4 g0 = LDH(ra.x & 0xffff), g1 = LDH(ra.x >> 16);
            uint4 g2 = LDH(ra.y & 0xffff), g3 = LDH(ra.y >> 16);
            uint4 g4 = LDH(ra.z & 0xffff), g5 = LDH(ra.z >> 16);
            uint4 g6 = LDH(ra.w & 0xffff), g7 = LDH(ra.w >> 16);
            ACC8(accA, g0); ACC8(accA, g1); ACC8(accA, g2); ACC8(accA, g3);
            ACC8(accA, g4); ACC8(accA, g5); ACC8(accA, g6); ACC8(accA, g7);
        }
        for (; iB + 8 <= endB; iB += 8) {
            uint4 rb = *(const uint4*)(rowB + iB);
            uint4 k0 = LDH(rb.x & 0xffff), k1 = LDH(rb.x >> 16);
            uint4 k2 = LDH(rb.y & 0xffff), k3 = LDH(rb.y >> 16);
            uint4 k4 = LDH(rb.z & 0xffff), k5 = LDH(rb.z >> 16);
            uint4 k6 = LDH(rb.w & 0xffff), k7 = LDH(rb.w >> 16);
            ACC8(accB, k0); ACC8(accB, k1); ACC8(accB, k2); ACC8(accB, k3);
            ACC8(accB, k4); ACC8(accB, k5); ACC8(accB, k6); ACC8(accB, k7);
        }
        for (; iA < endA; ++iA) { uint4 g = LDH(rowA[iA]); ACC8(accA, g); }
        for (; iB < endB; ++iB) { uint4 k = LDH(rowB[iB]); ACC8(accB, k); }

        const float alpha = a1[0];
        float bias[8];
        #pragma unroll
        for (int j = 0; j < 8; ++j) bias[j] = b[l16 * 8 + j];

        float ndA = rsqrtf((float)(dgA < 1 ? 1 : dgA));
        float ndB = rsqrtf((float)(dgB < 1 ? 1 : dgB));
        float xA[8], xB[8];
        #pragma unroll
        for (int j = 0; j < 8; ++j) {
            float va = accA[j] * ndA + bias[j];
            va = (va >= 0.f) ? va : alpha * va;
            xA[j] = va; lsum[j] += va; lsq[j] += va * va;
            float vb = accB[j] * ndB + bias[j];
            vb = (vb >= 0.f) ? vb : alpha * vb;
            xB[j] = vb; lsum[j] += vb; lsq[j] += vb * vb;
        }
        uint4 oA, oB;
        oA.x = cvt_pk_bf16(xA[0], xA[1]); oA.y = cvt_pk_bf16(xA[2], xA[3]);
        oA.z = cvt_pk_bf16(xA[4], xA[5]); oA.w = cvt_pk_bf16(xA[6], xA[7]);
        oB.x = cvt_pk_bf16(xB[0], xB[1]); oB.y = cvt_pk_bf16(xB[2], xB[3]);
        oB.z = cvt_pk_bf16(xB[4], xB[5]); oB.w = cvt_pk_bf16(xB[6], xB[7]);
        *(uint4*)(h2 + (size_t)n0 * D + coff) = oA;
        *(uint4*)(h2 + (size_t)n1 * D + coff) = oB;
    }

    // BN partials: reduce across 4 slots in wave, then 4 waves, then atomics
    #pragma unroll
    for (int j = 0; j < 8; ++j) {
        lsum[j] += __shfl_xor(lsum[j], 16);
        lsum[j] += __shfl_xor(lsum[j], 32);
        lsq[j]  += __shfl_xor(lsq[j], 16);
        lsq[j]  += __shfl_xor(lsq[j], 32);
    }
    __shared__ float red[4][256];
    const int wave = tid >> 6;
    const int lane = tid & 63;
    if (lane < 16) {
        #pragma unroll
        for (int j = 0; j < 8; ++j) {
            red[wave][l16 * 16 + j]     = lsum[j];
            red[wave][l16 * 16 + 8 + j] = lsq[j];
        }
    }
    __syncthreads();
    {
        float tot = red[0][tid] + red[1][tid] + red[2][tid] + red[3][tid];
        int l = tid >> 4;
        int v = tid & 15;
        int dim = l * 8 + (v & 7);
        int rep = (blockIdx.x & 3) * D;    // 4-way replicated accumulators
        if (v < 8) atomicAdd(&bn_sum[rep + dim], tot);
        else       atomicAdd(&bn_sumsq[rep + dim], tot);
    }
}

// ---------- kernel 4: BN finalize + PReLU (bf16 in, fp32 out) ----------
__global__ __launch_bounds__(256) void final_kernel(const unsigned short* __restrict__ h2,
                                                    const float* __restrict__ bn_sum,
                                                    const float* __restrict__ bn_sumsq,
                                                    const float* __restrict__ gamma,
                                                    const float* __restrict__ beta,
                                                    const float* __restrict__ a2,
                                                    float* __restrict__ out) {
    int i8 = blockIdx.x * 256 + threadIdx.x;   // one thread per 8 elements
    if (i8 < N_NODES * D / 8) {
        int dbase = (i8 * 8) & (D - 1);
        const float invN = 1.0f / (float)N_NODES;
        const float alpha = a2[0];
        uint4 v = ((const uint4*)h2)[i8];
        float xv[8] = { bf_lo(v.x), bf_hi(v.x), bf_lo(v.y), bf_hi(v.y),
                        bf_lo(v.z), bf_hi(v.z), bf_lo(v.w), bf_hi(v.w) };
        float r[8];
        #pragma unroll
        for (int j = 0; j < 8; ++j) {
            int d = dbase + j;
            float sm = bn_sum[d] + bn_sum[D + d] + bn_sum[2 * D + d] + bn_sum[3 * D + d];
            float sq = bn_sumsq[d] + bn_sumsq[D + d] + bn_sumsq[2 * D + d] + bn_sumsq[3 * D + d];
            float mean = sm * invN;
            float var  = sq * invN - mean * mean;
            float inv  = rsqrtf(var + BN_EPS);
            float t = (xv[j] - mean) * inv * gamma[d] + beta[d];
            r[j] = (t >= 0.f) ? t : alpha * t;
        }
        float4* po = (float4*)(out + (size_t)i8 * 8);
        po[0] = make_float4(r[0], r[1], r[2], r[3]);
        po[1] = make_float4(r[4], r[5], r[6], r[7]);
    }
}

extern "C" void kernel_launch(void* const* d_in, const int* in_sizes, int n_in,
                              void* d_out, int out_size, void* d_ws, size_t ws_size,
                              hipStream_t stream) {
    const float* feat  = (const float*)d_in[0];
    const int*   src   = (const int*)  d_in[1];
    const int*   dst   = (const int*)  d_in[2];
    const float* W     = (const float*)d_in[3];
    const float* b     = (const float*)d_in[4];
    const float* a1    = (const float*)d_in[5];
    const float* gamma = (const float*)d_in[6];
    const float* beta  = (const float*)d_in[7];
    const float* a2    = (const float*)d_in[8];
    float* out = (float*)d_out;

    // Workspace layout (bytes). Only first 5120 B zeroed:
    //   gdbase (512) | gsbase (512) | bn_sum (2048) | bn_sumsq (2048)
    char* ws = (char*)d_ws;
    int*            gdbase    = (int*)(ws + 0);
    int*            gsbase    = (int*)(ws + 512);
    float*          bn_sum    = (float*)(ws + 1024);
    float*          bn_sumsq  = (float*)(ws + 3072);
    int*            cnt       = (int*)(ws + 5120);                // 200192
    unsigned short* ell       = (unsigned short*)(ws + 405120);   // 6.4 MB
    unsigned short* h         = (unsigned short*)(ws + 6805120);  // 12.8 MB bf16
    unsigned short* h2        = (unsigned short*)(ws + 19605120); // 12.8 MB bf16
    unsigned*       dbkt      = (unsigned*)(ws + 32405120);       // 128*8192*4 = 4 MB
    unsigned short* sbkt      = (unsigned short*)(ws + 36599424); // 128*8192*2 = 2 MB

    hipMemsetAsync(ws, 0, 5120, stream);

    // A||2) bucket (256 blocks) concurrent with proj (782 blocks)
    bucket_proj_kernel<<<A_BLOCKS + PROJ_TILES, 256, 0, stream>>>(
        src, dst, gdbase, gsbase, dbkt, sbkt, feat, W, h);

    // B) single-writer ELL build + cnt + in-place h *= rsqrt(out-degree)
    build_kernel<<<2 * BINS, 1024, 0, stream>>>(gdbase, gsbase, dbkt, sbkt,
                                                ell, cnt, h);

    // 3) SpMM gather (pure adds, 16-deep MLP) + BN partials (4-way replicated)
    spmm_kernel<<<SPMM_BLOCKS, 256, 0, stream>>>(cnt, ell, h, b, a1, h2,
                                                 bn_sum, bn_sumsq);

    // 4) BN finalize + PReLU
    final_kernel<<<(N_NODES * D / 8 + 255) / 256, 256, 0, stream>>>(h2, bn_sum, bn_sumsq,
                                                                    gamma, beta, a2, out);
}